// Round 1
// baseline (8327.096 us; speedup 1.0000x reference)
//
#include <hip/hip_runtime.h>
#include <hip/hip_bf16.h>
#include <math.h>

#define EPSV 1e-8f

__device__ __forceinline__ float dsmall(float d){ return d > EPSV ? d : EPSV; }
__device__ __forceinline__ float sigf(float x){ return 1.f/(1.f+expf(-x)); }

// ---------------------------------------------------------------------------
// Transpose: W (R x C) -> WT (C x R)
// ---------------------------------------------------------------------------
__global__ __launch_bounds__(1024) void k_transpose(const float* __restrict__ W,
                                                    float* __restrict__ WT, int R, int C){
  __shared__ float t[32][33];
  int rb = blockIdx.y*32, cb = blockIdx.x*32;
  int r = rb + threadIdx.y, c = cb + threadIdx.x;
  if (r < R && c < C) t[threadIdx.y][threadIdx.x] = W[(size_t)r*C + c];
  __syncthreads();
  int rr = cb + threadIdx.y, cc = rb + threadIdx.x;
  if (rr < C && cc < R) WT[(size_t)rr*R + cc] = t[threadIdx.x][threadIdx.y];
}

// ---------------------------------------------------------------------------
// Generic z-batched tiled GEMM-like kernel. 64x64 tile, 256 thr, 4x4/thread.
// MODE 0: C=A(MxK)@B(NxK)^T + bias[n]
// MODE 1: C=(A*wscale^2)(MxK)@B(NxK)^T / dsmall(U[m]*V[n])
// MODE 2: C=A(MxK)@B(KxN) / dsmall(U[m])
// MODE 3: C=max_k A(MxK)*B(KxN)
// MODE 4: C=A(KxM)^T@B(KxN) / dsmall(U[m])
// MODE 5: C=max_k A(KxM)^T*B(KxN)
// ---------------------------------------------------------------------------
template<int MODE>
__global__ __launch_bounds__(256) void k_gemm(
    const float* __restrict__ A0, int lda, long long sAo, long long sAi,
    const float* __restrict__ B0, int ldb, long long sBo, long long sBi,
    float* __restrict__ C0, int ldc, long long sCo, long long sCi,
    const float* __restrict__ W0, long long sWo, long long sWi,
    const float* __restrict__ U0, long long sUo, long long sUi,
    const float* __restrict__ V0, long long sVo, long long sVi,
    const float* __restrict__ bias,
    int M, int N, int K, int zdiv)
{
  const int z = blockIdx.z, zo = z / zdiv, zi = z % zdiv;
  const float* A = A0 + zo*sAo + zi*sAi;
  const float* B = B0 + zo*sBo + zi*sBi;
  float* C = C0 + zo*sCo + zi*sCi;
  const float* Wv = W0 ? (W0 + zo*sWo + zi*sWi) : nullptr;
  const float* U  = U0 ? (U0 + zo*sUo + zi*sUi) : nullptr;
  const float* V  = V0 ? (V0 + zo*sVo + zi*sVi) : nullptr;

  __shared__ float As[16][68];
  __shared__ float Bs[16][68];
  const int mb = blockIdx.y*64, nb = blockIdx.x*64;
  const int tid = threadIdx.x;
  const int tx = tid & 15, ty = tid >> 4;
  const bool ISMAX = (MODE==3 || MODE==5);

  float acc[4][4];
  #pragma unroll
  for (int i=0;i<4;i++)
    #pragma unroll
    for (int j=0;j<4;j++) acc[i][j] = ISMAX ? -INFINITY : 0.f;

  for (int kt = 0; kt < K; kt += 16) {
    // ---- stage A ----
    if (MODE <= 3) {              // A is M x K row-major
      int ka = tid & 15, ma = tid >> 4;
      #pragma unroll
      for (int q=0;q<4;q++){
        int m = ma + q*16;
        float v = 0.f;
        if (mb+m < M && kt+ka < K){
          v = A[(size_t)(mb+m)*lda + kt+ka];
          if (MODE==1 && Wv){ float w = Wv[kt+ka]; v *= w*w; }
        }
        As[ka][m] = v;
      }
    } else {                      // A is K x M row-major (aTb)
      int ma = tid & 63, ka = tid >> 6;
      #pragma unroll
      for (int q=0;q<4;q++){
        int k = ka + q*4;
        float v = 0.f;
        if (kt+k < K && mb+ma < M) v = A[(size_t)(kt+k)*lda + mb+ma];
        As[k][ma] = v;
      }
    }
    // ---- stage B ----
    if (MODE <= 1) {              // B is N x K row-major (B^T gemm)
      int kb = tid & 15, nbi = tid >> 4;
      #pragma unroll
      for (int q=0;q<4;q++){
        int n = nbi + q*16;
        float v = 0.f;
        if (nb+n < N && kt+kb < K) v = B[(size_t)(nb+n)*ldb + kt+kb];
        Bs[kb][n] = v;
      }
    } else {                      // B is K x N row-major
      int nbi = tid & 63, kb = tid >> 6;
      #pragma unroll
      for (int q=0;q<4;q++){
        int k = kb + q*4;
        float v = 0.f;
        if (kt+k < K && nb+nbi < N) v = B[(size_t)(kt+k)*ldb + nb+nbi];
        Bs[k][nbi] = v;
      }
    }
    __syncthreads();
    #pragma unroll
    for (int k=0;k<16;k++){
      float a[4], bv[4];
      #pragma unroll
      for (int i=0;i<4;i++) a[i] = As[k][ty*4+i];
      #pragma unroll
      for (int j=0;j<4;j++) bv[j] = Bs[k][tx*4+j];
      #pragma unroll
      for (int i=0;i<4;i++)
        #pragma unroll
        for (int j=0;j<4;j++){
          if (ISMAX) acc[i][j] = fmaxf(acc[i][j], a[i]*bv[j]);
          else       acc[i][j] += a[i]*bv[j];
        }
    }
    __syncthreads();
  }
  // ---- epilogue ----
  #pragma unroll
  for (int i=0;i<4;i++){
    int m = mb + ty*4 + i;
    if (m >= M) continue;
    #pragma unroll
    for (int j=0;j<4;j++){
      int n = nb + tx*4 + j;
      if (n >= N) continue;
      float v = acc[i][j];
      if (MODE==0){ if (bias) v += bias[n]; }
      else if (MODE==1){ v = v / dsmall(U[m]*V[n]); }
      else if (MODE==2 || MODE==4){ v = v / dsmall(U[m]); }
      C[(size_t)m*ldc + n] = v;
    }
  }
}

// ---------------------------------------------------------------------------
// LSTM scan: one WG per (seq, dir). 512 threads, thread owns gates 2t,2t+1.
// PRE: (8*256, 1024) per direction. WT: (256,1024) = Whh^T.
// HSo: (8,256,512) [seq][t][dir*256+h] or null. HTo: (8,2,256) or null.
// ---------------------------------------------------------------------------
__global__ __launch_bounds__(512) void k_scan(
    const float* __restrict__ PREf, const float* __restrict__ PREb,
    const float* __restrict__ WTf, const float* __restrict__ WTb,
    float* __restrict__ HSo, float* __restrict__ HTo)
{
  const int s = blockIdx.x >> 1, d = blockIdx.x & 1;
  const float* PRE = d ? PREb : PREf;
  const float* WT  = d ? WTb  : WTf;
  __shared__ __align__(16) float h[256];
  __shared__ float gate[1024];
  const int t2 = threadIdx.x;
  const int g0 = t2*2;
  if (t2 < 256) h[t2] = 0.f;
  float c = 0.f;
  __syncthreads();
  for (int tt = 0; tt < 256; ++tt) {
    const int t = d ? 255 - tt : tt;
    const float2 pv = *(const float2*)&PRE[((size_t)(s*256 + t))*1024 + g0];
    float a0 = pv.x, a1 = pv.y;
    #pragma unroll 8
    for (int k = 0; k < 256; k += 4) {
      float4 hv = *(const float4*)&h[k];
      float2 w0 = *(const float2*)&WT[(size_t)(k+0)*1024 + g0];
      float2 w1 = *(const float2*)&WT[(size_t)(k+1)*1024 + g0];
      float2 w2 = *(const float2*)&WT[(size_t)(k+2)*1024 + g0];
      float2 w3 = *(const float2*)&WT[(size_t)(k+3)*1024 + g0];
      a0 += hv.x*w0.x + hv.y*w1.x + hv.z*w2.x + hv.w*w3.x;
      a1 += hv.x*w0.y + hv.y*w1.y + hv.z*w2.y + hv.w*w3.y;
    }
    gate[g0] = a0; gate[g0+1] = a1;
    __syncthreads();
    if (t2 < 256) {
      float ig = sigf(gate[t2]);
      float fg = sigf(gate[256+t2]);
      float gg = tanhf(gate[512+t2]);
      float og = sigf(gate[768+t2]);
      c = fg*c + ig*gg;
      float hn = og*tanhf(c);
      h[t2] = hn;
      if (HSo) HSo[((size_t)(s*256 + t))*512 + d*256 + t2] = hn;
    }
    __syncthreads();
  }
  if (HTo && t2 < 256) HTo[((size_t)(s*2+d))*256 + t2] = h[t2];
}

// ---------------------------------------------------------------------------
// Row L2 norms of the 4096 (seq,dir,i) hidden rows.
// ---------------------------------------------------------------------------
__global__ __launch_bounds__(256) void k_rownorm(const float* __restrict__ HS_,
                                                 float* __restrict__ NORM_){
  int r = blockIdx.x*4 + (threadIdx.x >> 6);
  int lane = threadIdx.x & 63;
  int seq = r >> 9, d = (r >> 8) & 1, i = r & 255;
  const float* row = HS_ + ((size_t)(seq*256 + i))*512 + d*256;
  float s = 0.f;
  #pragma unroll
  for (int q=0;q<4;q++){ float v = row[lane + 64*q]; s += v*v; }
  for (int off=32; off; off>>=1) s += __shfl_xor(s, off, 64);
  if (lane == 0) NORM_[r] = sqrtf(s);
}

// ---------------------------------------------------------------------------
// Row sum+max reduction (cols elements per row, 4 rows/block)
// ---------------------------------------------------------------------------
__global__ __launch_bounds__(256) void k_rowred(const float* __restrict__ in,
                                                float* __restrict__ osum,
                                                float* __restrict__ omax, int cols){
  int r = blockIdx.x*4 + (threadIdx.x >> 6);
  int lane = threadIdx.x & 63;
  const float* row = in + (size_t)r*cols;
  float s = 0.f, m = -INFINITY;
  for (int cidx=lane; cidx<cols; cidx+=64){ float v=row[cidx]; s += v; m = fmaxf(m,v); }
  for (int off=32; off; off>>=1){ s += __shfl_xor(s,off,64); m = fmaxf(m, __shfl_xor(m,off,64)); }
  if (lane == 0){ if (osum) osum[r] = s; if (omax) omax[r] = m; }
}

// Column sum+max reduction over nrows, 256 cols, one block per z.
__global__ __launch_bounds__(256) void k_colred(const float* __restrict__ in0, long long zstride,
                                                int nrows, int ld,
                                                float* __restrict__ osum, float* __restrict__ omax){
  const float* in = in0 + (size_t)blockIdx.z*zstride;
  int j = threadIdx.x;
  float s = 0.f, m = -INFINITY;
  for (int r=0;r<nrows;r++){ float v = in[(size_t)r*ld + j]; s += v; m = fmaxf(m,v); }
  if (osum) osum[blockIdx.z*256 + j] = s;
  if (omax) omax[blockIdx.z*256 + j] = m;
}

// ---------------------------------------------------------------------------
// Weighted norms for pairwise matching: out[side][d][b][l][i]
// ---------------------------------------------------------------------------
__global__ __launch_bounds__(256) void k_wnorm(const float* __restrict__ HS_,
                                               const float* __restrict__ w3, const float* __restrict__ w4,
                                               float* __restrict__ WN1_, float* __restrict__ WN2_){
  int rid = blockIdx.x*4 + (threadIdx.x >> 6);
  int lane = threadIdx.x & 63;
  int side = rid / 20480; int rem = rid % 20480;
  int d = rem / 10240; int rem2 = rem % 10240;
  int b = rem2 / 2560; int l = (rem2 / 256) % 10; int i = rem2 & 255;
  int seq = side ? 4+b : b;
  const float* row = HS_ + ((size_t)(seq*256 + i))*512 + d*256;
  const float* w = (d ? w4 : w3) + l*256;
  float s = 0.f;
  #pragma unroll
  for (int q=0;q<4;q++){ float wv = w[lane+64*q]; float v = row[lane+64*q]; s += wv*wv*v*v; }
  for (int off=32; off; off>>=1) s += __shfl_xor(s, off, 64);
  if (lane == 0) (side ? WN2_ : WN1_)[rem] = sqrtf(s);
}

// ---------------------------------------------------------------------------
// Assemble mv rows (62 channels) incl. the 40 mp_match channels.
// Block per (side,b,i); 4 waves = 4 (vec,w) pairs.
// ---------------------------------------------------------------------------
__global__ __launch_bounds__(256) void k_mv(
    const float* __restrict__ HS_, const float* __restrict__ MEANH_, const float* __restrict__ MEANP_,
    const float* __restrict__ XH_, const float* __restrict__ XP_,
    const float* __restrict__ RS_, const float* __restrict__ RMAX_,
    const float* __restrict__ CS_, const float* __restrict__ CMAX_,
    const float* __restrict__ MMR_, const float* __restrict__ MMC_,
    const float* __restrict__ w5, const float* __restrict__ w6,
    const float* __restrict__ w7, const float* __restrict__ w8,
    float* __restrict__ MV_)
{
  const int blk = blockIdx.x;
  const int side = blk >> 10, b = (blk >> 8) & 3, i = blk & 255;
  const int wv = threadIdx.x >> 6, lane = threadIdx.x & 63;
  float* mvrow = MV_ + (size_t)blk*62;

  if (threadIdx.x == 0){
    const float* rmax = side ? CMAX_ : RMAX_;
    const float* rsum = side ? CS_   : RS_;
    mvrow[0] = rmax[b*256 + i];              // att_fw max
    mvrow[1] = rsum[b*256 + i] * (1.f/256.f);// att_fw mean
  }
  if (threadIdx.x < 20){
    int dd = threadIdx.x / 10, l = threadIdx.x % 10;
    const float* mm = side ? MMC_ : MMR_;
    mvrow[2 + dd*10 + l] = mm[dd*10240 + (b*10 + l)*256 + i];
  }
  const int d = wv & 1;                      // pairs 0,2 fw; 1,3 bw
  const int seq = side ? 4+b : b;
  const float* arow = HS_ + ((size_t)(seq*256 + i))*512 + d*256;
  const float* Mside = side ? MEANP_ : MEANH_;
  const float* Xside = side ? XP_ : XH_;
  const float* brow = (wv < 2 ? Mside : Xside) + (size_t)d*262144 + (size_t)b*65536 + (size_t)i*256;
  const float* wp = (wv==0) ? w5 : (wv==1) ? w6 : (wv==2) ? w7 : w8;

  float av[4], bv[4];
  #pragma unroll
  for (int q=0;q<4;q++){ av[q] = arow[lane+64*q]; bv[q] = brow[lane+64*q]; }
  for (int l=0;l<10;l++){
    const float* wrow = wp + l*256;
    float s1=0.f, s2=0.f, s3=0.f;
    #pragma unroll
    for (int q=0;q<4;q++){
      float w = wrow[lane+64*q]; float w2v = w*w;
      s1 += w2v*av[q]*bv[q]; s2 += w2v*av[q]*av[q]; s3 += w2v*bv[q]*bv[q];
    }
    for (int off=32; off; off>>=1){
      s1 += __shfl_xor(s1,off,64); s2 += __shfl_xor(s2,off,64); s3 += __shfl_xor(s3,off,64);
    }
    if (lane == 0) mvrow[22 + wv*10 + l] = s1 / fmaxf(sqrtf(s2)*sqrtf(s3), EPSV);
  }
}

// ---------------------------------------------------------------------------
// Mean over time of left/right: XM[b][side*300+d]
// ---------------------------------------------------------------------------
__global__ void k_means(const float* __restrict__ L, const float* __restrict__ R,
                        float* __restrict__ XM){
  int b = blockIdx.x & 3, sideR = blockIdx.x >> 2;
  const float* src = sideR ? R : L;
  int dch = threadIdx.x;
  if (dch >= 300) return;
  float s = 0.f;
  for (int t=0;t<256;t++) s += src[((size_t)(b*256 + t))*300 + dch];
  XM[b*600 + sideR*300 + dch] = s*(1.f/256.f);
}

// ---------------------------------------------------------------------------
// Head: fc1 (tanh), fc2
// ---------------------------------------------------------------------------
__global__ __launch_bounds__(512) void k_fc1(const float* __restrict__ HT_,
                                             const float* __restrict__ XM,
                                             const float* __restrict__ W1T,
                                             const float* __restrict__ b1,
                                             float* __restrict__ X2){
  __shared__ float x[1626];
  int b = blockIdx.x, t = threadIdx.x;
  if (t < 256){
    x[t]       = HT_[(b*2+0)*256 + t];
    x[256+t]   = HT_[(b*2+1)*256 + t];
    x[512+t]   = HT_[((4+b)*2+0)*256 + t];
    x[768+t]   = HT_[((4+b)*2+1)*256 + t];
  }
  if (t == 0){ x[1024] = 0.5f; x[1025] = 0.5f; }
  if (t < 300){ x[1026+t] = XM[b*600 + t]; x[1326+t] = XM[b*600 + 300 + t]; }
  __syncthreads();
  float acc = b1[t];
  for (int k=0;k<1626;k++) acc += x[k]*W1T[(size_t)k*512 + t];
  X2[b*512 + t] = tanhf(acc);
}

__global__ void k_fc2(const float* __restrict__ X2, const float* __restrict__ W2,
                      const float* __restrict__ b2, float* __restrict__ out){
  int b = blockIdx.x, o = threadIdx.x;
  if (o >= 22) return;
  float acc = b2[o];
  const float* xr = X2 + b*512;
  const float* wr = W2 + (size_t)o*512;
  for (int k=0;k<512;k++) acc += xr[k]*wr[k];
  out[b*22 + o] = acc;
}

// ---------------------------------------------------------------------------
extern "C" void kernel_launch(void* const* d_in, const int* in_sizes, int n_in,
                              void* d_out, int out_size, void* d_ws, size_t ws_size,
                              hipStream_t stream) {
  const float* left  = (const float*)d_in[0];
  const float* right = (const float*)d_in[1];
  const float* cWihF = (const float*)d_in[2];
  const float* cWhhF = (const float*)d_in[3];
  const float* cbF   = (const float*)d_in[4];
  const float* cWihB = (const float*)d_in[5];
  const float* cWhhB = (const float*)d_in[6];
  const float* cbB   = (const float*)d_in[7];
  const float* aWihF = (const float*)d_in[8];
  const float* aWhhF = (const float*)d_in[9];
  const float* abF   = (const float*)d_in[10];
  const float* aWihB = (const float*)d_in[11];
  const float* aWhhB = (const float*)d_in[12];
  const float* abB   = (const float*)d_in[13];
  const float* w3 = (const float*)d_in[14];
  const float* w4 = (const float*)d_in[15];
  const float* w5 = (const float*)d_in[16];
  const float* w6 = (const float*)d_in[17];
  const float* w7 = (const float*)d_in[18];
  const float* w8 = (const float*)d_in[19];
  const float* fc1W = (const float*)d_in[20];
  const float* fc1b = (const float*)d_in[21];
  const float* fc2W = (const float*)d_in[22];
  const float* fc2b = (const float*)d_in[23];
  float* out = (float*)d_out;
  float* ws = (float*)d_ws;

  // workspace layout (floats)
  float* WT    = ws;                 // 4 * 262144  (ctx_f, ctx_b, agg_f, agg_b)
  float* PREf  = ws + 1048576;       // 2097152
  float* PREb  = ws + 3145728;       // 2097152
  float* HS    = ws + 5242880;       // 1048576  (8,256,512)
  float* NORM  = ws + 6291456;       // 4096     [(seq*2+d)*256+i]
  float* ATT   = ws + 6295552;       // 524288   [d][b][i][j]
  float* RS    = ws + 6819840;       // 2048     [(d*4+b)*256+i]
  float* RMAX  = ws + 6821888;       // 2048
  float* CS    = ws + 6823936;       // 2048
  float* CMAX  = ws + 6825984;       // 2048
  float* MEANH = ws + 6828032;       // 524288   [d][b][i][h]
  float* MEANP = ws + 7352320;       // 524288   [d][b][j][h]
  float* XH    = ws + 7876608;       // 524288
  float* XP    = ws + 8400896;       // 524288
  float* WN1   = ws + 8925184;       // 20480    [d][b][l][i]
  float* WN2   = ws + 8945664;       // 20480
  float* MM    = ws + 8966144;       // 2621440  [b][l][i][j] (per dir, reused)
  float* MMR   = ws + 11587584;      // 20480    [d][b][l][i]
  float* MMC   = ws + 11608064;      // 20480
  float* MV    = ws + 11628544;      // 126976   (2048,62)
  float* HT    = ws + 11755520;      // 4096     [(seq*2+d)*256+j]
  float* XM    = ws + 11759616;      // 2400
  float* X2    = ws + 11762016;      // 2048
  float* W1T   = ws + 11764064;      // 832512

  // 1. transposes
  k_transpose<<<dim3(8,32),  dim3(32,32), 0, stream>>>(cWhhF, WT + 0,      1024, 256);
  k_transpose<<<dim3(8,32),  dim3(32,32), 0, stream>>>(cWhhB, WT + 262144, 1024, 256);
  k_transpose<<<dim3(8,32),  dim3(32,32), 0, stream>>>(aWhhF, WT + 524288, 1024, 256);
  k_transpose<<<dim3(8,32),  dim3(32,32), 0, stream>>>(aWhhB, WT + 786432, 1024, 256);
  k_transpose<<<dim3(51,16), dim3(32,32), 0, stream>>>(fc1W, W1T, 512, 1626);

  // 2. ctx input projections (x @ Wih^T + b)
  k_gemm<0><<<dim3(16,16,1),256,0,stream>>>(left, 300,0,0,  cWihF,300,0,0,  PREf,           1024,0,0,
      nullptr,0,0, nullptr,0,0, nullptr,0,0, cbF, 1024,1024,300, 1);
  k_gemm<0><<<dim3(16,16,1),256,0,stream>>>(right,300,0,0,  cWihF,300,0,0,  PREf+1048576,   1024,0,0,
      nullptr,0,0, nullptr,0,0, nullptr,0,0, cbF, 1024,1024,300, 1);
  k_gemm<0><<<dim3(16,16,1),256,0,stream>>>(left, 300,0,0,  cWihB,300,0,0,  PREb,           1024,0,0,
      nullptr,0,0, nullptr,0,0, nullptr,0,0, cbB, 1024,1024,300, 1);
  k_gemm<0><<<dim3(16,16,1),256,0,stream>>>(right,300,0,0,  cWihB,300,0,0,  PREb+1048576,   1024,0,0,
      nullptr,0,0, nullptr,0,0, nullptr,0,0, cbB, 1024,1024,300, 1);

  // 3. ctx scan
  k_scan<<<16,512,0,stream>>>(PREf, PREb, WT, WT+262144, HS, nullptr);

  // 4. row norms
  k_rownorm<<<1024,256,0,stream>>>(HS, NORM);

  // 5. att (cosine matrix), z = d*4+b
  k_gemm<1><<<dim3(4,4,8),256,0,stream>>>(HS,512,256,131072,  HS+524288,512,256,131072,
      ATT,256,262144,65536,  nullptr,0,0,  NORM,256,512,  NORM+2048,256,512,
      nullptr, 256,256,256, 4);

  // 6-7. att reductions
  k_rowred<<<512,256,0,stream>>>(ATT, RS, RMAX, 256);
  k_colred<<<dim3(1,1,8),256,0,stream>>>(ATT, 65536, 256, 256, CS, CMAX);

  // 8. attentive means and maxes
  k_gemm<2><<<dim3(4,4,8),256,0,stream>>>(ATT,256,262144,65536,  HS+524288,512,256,131072,
      MEANH,256,262144,65536,  nullptr,0,0,  RS,1024,256,  nullptr,0,0, nullptr, 256,256,256, 4);
  k_gemm<4><<<dim3(4,4,8),256,0,stream>>>(ATT,256,262144,65536,  HS,512,256,131072,
      MEANP,256,262144,65536,  nullptr,0,0,  CS,1024,256,  nullptr,0,0, nullptr, 256,256,256, 4);
  k_gemm<3><<<dim3(4,4,8),256,0,stream>>>(ATT,256,262144,65536,  HS+524288,512,256,131072,
      XH,256,262144,65536,  nullptr,0,0,  nullptr,0,0,  nullptr,0,0, nullptr, 256,256,256, 4);
  k_gemm<5><<<dim3(4,4,8),256,0,stream>>>(ATT,256,262144,65536,  HS,512,256,131072,
      XP,256,262144,65536,  nullptr,0,0,  nullptr,0,0,  nullptr,0,0, nullptr, 256,256,256, 4);

  // 9. weighted norms
  k_wnorm<<<10240,256,0,stream>>>(HS, w3, w4, WN1, WN2);

  // 10-13. pairwise mm (fw then bw, buffer reused), z = b*10+l
  k_gemm<1><<<dim3(4,4,40),256,0,stream>>>(HS,512,131072,0,  HS+524288,512,131072,0,
      MM,256,655360,65536,  w3,0,256,  WN1,2560,256,  WN2,2560,256,
      nullptr, 256,256,256, 10);
  k_rowred<<<2560,256,0,stream>>>(MM, nullptr, MMR, 256);
  k_colred<<<dim3(1,1,40),256,0,stream>>>(MM, 65536, 256, 256, nullptr, MMC);
  k_gemm<1><<<dim3(4,4,40),256,0,stream>>>(HS+256,512,131072,0,  HS+524288+256,512,131072,0,
      MM,256,655360,65536,  w4,0,256,  WN1+10240,2560,256,  WN2+10240,2560,256,
      nullptr, 256,256,256, 10);
  k_rowred<<<2560,256,0,stream>>>(MM, nullptr, MMR+10240, 256);
  k_colred<<<dim3(1,1,40),256,0,stream>>>(MM, 65536, 256, 256, nullptr, MMC+10240);

  // 14. assemble mv (2048 rows x 62)
  k_mv<<<2048,256,0,stream>>>(HS, MEANH, MEANP, XH, XP, RS, RMAX, CS, CMAX,
                              MMR, MMC, w5, w6, w7, w8, MV);

  // 15. agg projections
  k_gemm<0><<<dim3(16,32,1),256,0,stream>>>(MV,62,0,0,  aWihF,62,0,0,  PREf,1024,0,0,
      nullptr,0,0, nullptr,0,0, nullptr,0,0, abF, 2048,1024,62, 1);
  k_gemm<0><<<dim3(16,32,1),256,0,stream>>>(MV,62,0,0,  aWihB,62,0,0,  PREb,1024,0,0,
      nullptr,0,0, nullptr,0,0, nullptr,0,0, abB, 2048,1024,62, 1);

  // 16. agg scan (keep only final h)
  k_scan<<<16,512,0,stream>>>(PREf, PREb, WT+524288, WT+786432, nullptr, HT);

  // 17-19. head
  k_means<<<8,320,0,stream>>>(left, right, XM);
  k_fc1<<<4,512,0,stream>>>(HT, XM, W1T, fc1b, X2);
  k_fc2<<<4,64,0,stream>>>(X2, fc2W, fc2b, out);
}

// Round 2
// 3524.566 us; speedup vs baseline: 2.3626x; 2.3626x over previous
//
#include <hip/hip_runtime.h>
#include <hip/hip_bf16.h>
#include <math.h>

#define EPSV 1e-8f

__device__ __forceinline__ float dsmall(float d){ return d > EPSV ? d : EPSV; }
__device__ __forceinline__ float sigf(float x){ return 1.f/(1.f+expf(-x)); }

// ---------------------------------------------------------------------------
// Transpose: W (R x C) -> WT (C x R)
// ---------------------------------------------------------------------------
__global__ __launch_bounds__(1024) void k_transpose(const float* __restrict__ W,
                                                    float* __restrict__ WT, int R, int C){
  __shared__ float t[32][33];
  int rb = blockIdx.y*32, cb = blockIdx.x*32;
  int r = rb + threadIdx.y, c = cb + threadIdx.x;
  if (r < R && c < C) t[threadIdx.y][threadIdx.x] = W[(size_t)r*C + c];
  __syncthreads();
  int rr = cb + threadIdx.y, cc = rb + threadIdx.x;
  if (rr < C && cc < R) WT[(size_t)rr*R + cc] = t[threadIdx.x][threadIdx.y];
}

// ---------------------------------------------------------------------------
// Generic z-batched tiled GEMM-like kernel. 64x64 tile, 256 thr, 4x4/thread.
// MODE 0: C=A(MxK)@B(NxK)^T + bias[n]
// MODE 1: C=(A*wscale^2)(MxK)@B(NxK)^T / dsmall(U[m]*V[n])
// MODE 2: C=A(MxK)@B(KxN) / dsmall(U[m])
// MODE 3: C=max_k A(MxK)*B(KxN)
// MODE 4: C=A(KxM)^T@B(KxN) / dsmall(U[m])
// MODE 5: C=max_k A(KxM)^T*B(KxN)
// ---------------------------------------------------------------------------
template<int MODE>
__global__ __launch_bounds__(256) void k_gemm(
    const float* __restrict__ A0, int lda, long long sAo, long long sAi,
    const float* __restrict__ B0, int ldb, long long sBo, long long sBi,
    float* __restrict__ C0, int ldc, long long sCo, long long sCi,
    const float* __restrict__ W0, long long sWo, long long sWi,
    const float* __restrict__ U0, long long sUo, long long sUi,
    const float* __restrict__ V0, long long sVo, long long sVi,
    const float* __restrict__ bias,
    int M, int N, int K, int zdiv)
{
  const int z = blockIdx.z, zo = z / zdiv, zi = z % zdiv;
  const float* A = A0 + zo*sAo + zi*sAi;
  const float* B = B0 + zo*sBo + zi*sBi;
  float* C = C0 + zo*sCo + zi*sCi;
  const float* Wv = W0 ? (W0 + zo*sWo + zi*sWi) : nullptr;
  const float* U  = U0 ? (U0 + zo*sUo + zi*sUi) : nullptr;
  const float* V  = V0 ? (V0 + zo*sVo + zi*sVi) : nullptr;

  __shared__ float As[16][68];
  __shared__ float Bs[16][68];
  const int mb = blockIdx.y*64, nb = blockIdx.x*64;
  const int tid = threadIdx.x;
  const int tx = tid & 15, ty = tid >> 4;
  const bool ISMAX = (MODE==3 || MODE==5);

  float acc[4][4];
  #pragma unroll
  for (int i=0;i<4;i++)
    #pragma unroll
    for (int j=0;j<4;j++) acc[i][j] = ISMAX ? -INFINITY : 0.f;

  for (int kt = 0; kt < K; kt += 16) {
    // ---- stage A ----
    if (MODE <= 3) {              // A is M x K row-major
      int ka = tid & 15, ma = tid >> 4;
      #pragma unroll
      for (int q=0;q<4;q++){
        int m = ma + q*16;
        float v = 0.f;
        if (mb+m < M && kt+ka < K){
          v = A[(size_t)(mb+m)*lda + kt+ka];
          if (MODE==1 && Wv){ float w = Wv[kt+ka]; v *= w*w; }
        }
        As[ka][m] = v;
      }
    } else {                      // A is K x M row-major (aTb)
      int ma = tid & 63, ka = tid >> 6;
      #pragma unroll
      for (int q=0;q<4;q++){
        int k = ka + q*4;
        float v = 0.f;
        if (kt+k < K && mb+ma < M) v = A[(size_t)(kt+k)*lda + mb+ma];
        As[k][ma] = v;
      }
    }
    // ---- stage B ----
    if (MODE <= 1) {              // B is N x K row-major (B^T gemm)
      int kb = tid & 15, nbi = tid >> 4;
      #pragma unroll
      for (int q=0;q<4;q++){
        int n = nbi + q*16;
        float v = 0.f;
        if (nb+n < N && kt+kb < K) v = B[(size_t)(nb+n)*ldb + kt+kb];
        Bs[kb][n] = v;
      }
    } else {                      // B is K x N row-major
      int nbi = tid & 63, kb = tid >> 6;
      #pragma unroll
      for (int q=0;q<4;q++){
        int k = kb + q*4;
        float v = 0.f;
        if (kt+k < K && nb+nbi < N) v = B[(size_t)(kt+k)*ldb + nb+nbi];
        Bs[k][nbi] = v;
      }
    }
    __syncthreads();
    #pragma unroll
    for (int k=0;k<16;k++){
      float a[4], bv[4];
      #pragma unroll
      for (int i=0;i<4;i++) a[i] = As[k][ty*4+i];
      #pragma unroll
      for (int j=0;j<4;j++) bv[j] = Bs[k][tx*4+j];
      #pragma unroll
      for (int i=0;i<4;i++)
        #pragma unroll
        for (int j=0;j<4;j++){
          if (ISMAX) acc[i][j] = fmaxf(acc[i][j], a[i]*bv[j]);
          else       acc[i][j] += a[i]*bv[j];
        }
    }
    __syncthreads();
  }
  // ---- epilogue ----
  #pragma unroll
  for (int i=0;i<4;i++){
    int m = mb + ty*4 + i;
    if (m >= M) continue;
    #pragma unroll
    for (int j=0;j<4;j++){
      int n = nb + tx*4 + j;
      if (n >= N) continue;
      float v = acc[i][j];
      if (MODE==0){ if (bias) v += bias[n]; }
      else if (MODE==1){ v = v / dsmall(U[m]*V[n]); }
      else if (MODE==2 || MODE==4){ v = v / dsmall(U[m]); }
      C[(size_t)m*ldc + n] = v;
    }
  }
}

// ---------------------------------------------------------------------------
// LSTM scan v2: 8 WGs per direction, LDS-resident weight slice, 8 seqs
// batched. Grid = 16 (dir = bx>>3, wg = bx&7). 512 threads.
// WG wg owns h indices [wg*32, wg*32+32) i.e. gate cols {gt*256+wg*32+j}.
// Per-step cross-WG h exchange through device-coherent Hbuf + atomic barrier.
// PRE: (8*256,1024) per dir. WT: (256,1024) = Whh^T per dir.
// Hbuf: [dir][parity][256 j][8 s] floats. cnt: [dir][256 steps] ints (zeroed).
// HSo: (8,256,512) [seq][t][dir*256+h] or null. HTo: (8dirseq,256) or null.
// ---------------------------------------------------------------------------
__global__ __launch_bounds__(512) void k_scan2(
    const float* __restrict__ PREf, const float* __restrict__ PREb,
    const float* __restrict__ WTf, const float* __restrict__ WTb,
    float* __restrict__ Hbuf, int* __restrict__ cnt,
    float* __restrict__ HSo, float* __restrict__ HTo)
{
  const int wg = blockIdx.x & 7;
  const int d  = blockIdx.x >> 3;
  const float* PRE = d ? PREb : PREf;
  const float* WT  = d ? WTb  : WTf;
  float* Hb = Hbuf + (size_t)d*2*2048;
  int* cn = cnt + d*256;

  __shared__ float Wl[256][128];   // 128 KB: Wl[k][gt*32+j]
  __shared__ float hl[256][8];     // 8 KB:  hl[k][s]
  __shared__ float red[2][4][32][16]; // 16 KB partial sums

  const int tid = threadIdx.x;
  // stage weight slice into LDS (once)
  for (int e = tid; e < 256*128; e += 512) {
    int k = e >> 7, c = e & 127;
    int gt = c >> 5, j = c & 31;
    Wl[k][c] = WT[(size_t)k*1024 + gt*256 + wg*32 + j];
  }
  for (int e = tid; e < 2048; e += 512) ((float*)hl)[e] = 0.f;
  __syncthreads();

  // matmul work item: p = seq-quad, kc = k-chunk, gq = gate-quad
  const int p  = tid >> 8;
  const int kc = (tid >> 5) & 7;
  const int gq = tid & 31;
  // activation work item (tid<256)
  const int as = tid >> 5, aj = tid & 31;
  float cst = 0.f;

  for (int tt = 0; tt < 256; ++tt) {
    const int t = d ? 255 - tt : tt;
    const int wp = (tt + 1) & 1;

    // prefetch PRE for activation phase (latency hidden under matmul)
    float pre0=0.f, pre1=0.f, pre2=0.f, pre3=0.f;
    if (tid < 256) {
      size_t base = ((size_t)(as*256 + t))*1024 + wg*32 + aj;
      pre0 = PRE[base];       pre1 = PRE[base + 256];
      pre2 = PRE[base + 512]; pre3 = PRE[base + 768];
    }

    // ---- gate matmul partials: acc[ds*4+dg] over 32 k of chunk kc ----
    float acc[16];
    #pragma unroll
    for (int i=0;i<16;i++) acc[i]=0.f;
    #pragma unroll 4
    for (int kk = 0; kk < 32; ++kk) {
      int k = kc*32 + kk;
      float4 hv = *(const float4*)&hl[k][p*4];
      float4 wv = *(const float4*)&Wl[k][gq*4];
      acc[ 0] += hv.x*wv.x; acc[ 1] += hv.x*wv.y; acc[ 2] += hv.x*wv.z; acc[ 3] += hv.x*wv.w;
      acc[ 4] += hv.y*wv.x; acc[ 5] += hv.y*wv.y; acc[ 6] += hv.y*wv.z; acc[ 7] += hv.y*wv.w;
      acc[ 8] += hv.z*wv.x; acc[ 9] += hv.z*wv.y; acc[10] += hv.z*wv.z; acc[11] += hv.z*wv.w;
      acc[12] += hv.w*wv.x; acc[13] += hv.w*wv.y; acc[14] += hv.w*wv.z; acc[15] += hv.w*wv.w;
    }
    // pair-reduce across kc parity within wave, then stash to LDS
    #pragma unroll
    for (int i=0;i<16;i++) acc[i] += __shfl_xor(acc[i], 32, 64);
    if ((tid & 32) == 0) {
      int kp = kc >> 1;
      #pragma unroll
      for (int i=0;i<16;i++) red[p][kp][gq][i] = acc[i];
    }
    __syncthreads();

    // ---- activation + h/c update (threads 0..255) ----
    if (tid < 256) {
      const int pp = as >> 2, ds = as & 3;
      float g[4];
      #pragma unroll
      for (int gt=0; gt<4; ++gt) {
        int gcol = gt*32 + aj;
        int gqq = gcol >> 2, dg = gcol & 3;
        int i = ds*4 + dg;
        g[gt] = red[pp][0][gqq][i] + red[pp][1][gqq][i]
              + red[pp][2][gqq][i] + red[pp][3][gqq][i];
      }
      g[0] += pre0; g[1] += pre1; g[2] += pre2; g[3] += pre3;
      float ig = sigf(g[0]), fg = sigf(g[1]), gg = tanhf(g[2]), og = sigf(g[3]);
      cst = fg*cst + ig*gg;
      float h = og*tanhf(cst);
      __hip_atomic_store(&Hb[wp*2048 + (wg*32 + aj)*8 + as], h,
                         __ATOMIC_RELAXED, __HIP_MEMORY_SCOPE_AGENT);
      if (HSo) HSo[((size_t)(as*256 + t))*512 + d*256 + wg*32 + aj] = h;
      if (HTo && tt == 255) HTo[((size_t)(as*2 + d))*256 + wg*32 + aj] = h;
    }
    __syncthreads();  // drains all stores (compiler emits vmcnt(0) pre-barrier)

    // ---- cross-WG arrive + wait ----
    if (tid == 0) {
      __hip_atomic_fetch_add(&cn[tt], 1, __ATOMIC_RELEASE, __HIP_MEMORY_SCOPE_AGENT);
      while (__hip_atomic_load(&cn[tt], __ATOMIC_RELAXED, __HIP_MEMORY_SCOPE_AGENT) < 8) {}
    }
    __syncthreads();

    // ---- reload full h into LDS ----
    for (int e = tid; e < 2048; e += 512)
      ((float*)hl)[e] = __hip_atomic_load(&Hb[wp*2048 + e],
                                          __ATOMIC_RELAXED, __HIP_MEMORY_SCOPE_AGENT);
    __syncthreads();
  }
}

// ---------------------------------------------------------------------------
// Row L2 norms of the 4096 (seq,dir,i) hidden rows.
// ---------------------------------------------------------------------------
__global__ __launch_bounds__(256) void k_rownorm(const float* __restrict__ HS_,
                                                 float* __restrict__ NORM_){
  int r = blockIdx.x*4 + (threadIdx.x >> 6);
  int lane = threadIdx.x & 63;
  int seq = r >> 9, d = (r >> 8) & 1, i = r & 255;
  const float* row = HS_ + ((size_t)(seq*256 + i))*512 + d*256;
  float s = 0.f;
  #pragma unroll
  for (int q=0;q<4;q++){ float v = row[lane + 64*q]; s += v*v; }
  for (int off=32; off; off>>=1) s += __shfl_xor(s, off, 64);
  if (lane == 0) NORM_[r] = sqrtf(s);
}

// ---------------------------------------------------------------------------
// Row sum+max reduction (cols elements per row, 4 rows/block)
// ---------------------------------------------------------------------------
__global__ __launch_bounds__(256) void k_rowred(const float* __restrict__ in,
                                                float* __restrict__ osum,
                                                float* __restrict__ omax, int cols){
  int r = blockIdx.x*4 + (threadIdx.x >> 6);
  int lane = threadIdx.x & 63;
  const float* row = in + (size_t)r*cols;
  float s = 0.f, m = -INFINITY;
  for (int cidx=lane; cidx<cols; cidx+=64){ float v=row[cidx]; s += v; m = fmaxf(m,v); }
  for (int off=32; off; off>>=1){ s += __shfl_xor(s,off,64); m = fmaxf(m, __shfl_xor(m,off,64)); }
  if (lane == 0){ if (osum) osum[r] = s; if (omax) omax[r] = m; }
}

// Column sum+max reduction over nrows, 256 cols, one block per z.
__global__ __launch_bounds__(256) void k_colred(const float* __restrict__ in0, long long zstride,
                                                int nrows, int ld,
                                                float* __restrict__ osum, float* __restrict__ omax){
  const float* in = in0 + (size_t)blockIdx.z*zstride;
  int j = threadIdx.x;
  float s = 0.f, m = -INFINITY;
  for (int r=0;r<nrows;r++){ float v = in[(size_t)r*ld + j]; s += v; m = fmaxf(m,v); }
  if (osum) osum[blockIdx.z*256 + j] = s;
  if (omax) omax[blockIdx.z*256 + j] = m;
}

// ---------------------------------------------------------------------------
// Weighted norms for pairwise matching: out[side][d][b][l][i]
// ---------------------------------------------------------------------------
__global__ __launch_bounds__(256) void k_wnorm(const float* __restrict__ HS_,
                                               const float* __restrict__ w3, const float* __restrict__ w4,
                                               float* __restrict__ WN1_, float* __restrict__ WN2_){
  int rid = blockIdx.x*4 + (threadIdx.x >> 6);
  int lane = threadIdx.x & 63;
  int side = rid / 20480; int rem = rid % 20480;
  int d = rem / 10240; int rem2 = rem % 10240;
  int b = rem2 / 2560; int l = (rem2 / 256) % 10; int i = rem2 & 255;
  int seq = side ? 4+b : b;
  const float* row = HS_ + ((size_t)(seq*256 + i))*512 + d*256;
  const float* w = (d ? w4 : w3) + l*256;
  float s = 0.f;
  #pragma unroll
  for (int q=0;q<4;q++){ float wv = w[lane+64*q]; float v = row[lane+64*q]; s += wv*wv*v*v; }
  for (int off=32; off; off>>=1) s += __shfl_xor(s, off, 64);
  if (lane == 0) (side ? WN2_ : WN1_)[rem] = sqrtf(s);
}

// ---------------------------------------------------------------------------
// Assemble mv rows (62 channels) incl. the 40 mp_match channels.
// Block per (side,b,i); 4 waves = 4 (vec,w) pairs.
// ---------------------------------------------------------------------------
__global__ __launch_bounds__(256) void k_mv(
    const float* __restrict__ HS_, const float* __restrict__ MEANH_, const float* __restrict__ MEANP_,
    const float* __restrict__ XH_, const float* __restrict__ XP_,
    const float* __restrict__ RS_, const float* __restrict__ RMAX_,
    const float* __restrict__ CS_, const float* __restrict__ CMAX_,
    const float* __restrict__ MMR_, const float* __restrict__ MMC_,
    const float* __restrict__ w5, const float* __restrict__ w6,
    const float* __restrict__ w7, const float* __restrict__ w8,
    float* __restrict__ MV_)
{
  const int blk = blockIdx.x;
  const int side = blk >> 10, b = (blk >> 8) & 3, i = blk & 255;
  const int wv = threadIdx.x >> 6, lane = threadIdx.x & 63;
  float* mvrow = MV_ + (size_t)blk*62;

  if (threadIdx.x == 0){
    const float* rmax = side ? CMAX_ : RMAX_;
    const float* rsum = side ? CS_   : RS_;
    mvrow[0] = rmax[b*256 + i];              // att_fw max
    mvrow[1] = rsum[b*256 + i] * (1.f/256.f);// att_fw mean
  }
  if (threadIdx.x < 20){
    int dd = threadIdx.x / 10, l = threadIdx.x % 10;
    const float* mm = side ? MMC_ : MMR_;
    mvrow[2 + dd*10 + l] = mm[dd*10240 + (b*10 + l)*256 + i];
  }
  const int d = wv & 1;                      // pairs 0,2 fw; 1,3 bw
  const int seq = side ? 4+b : b;
  const float* arow = HS_ + ((size_t)(seq*256 + i))*512 + d*256;
  const float* Mside = side ? MEANP_ : MEANH_;
  const float* Xside = side ? XP_ : XH_;
  const float* brow = (wv < 2 ? Mside : Xside) + (size_t)d*262144 + (size_t)b*65536 + (size_t)i*256;
  const float* wp = (wv==0) ? w5 : (wv==1) ? w6 : (wv==2) ? w7 : w8;

  float av[4], bv[4];
  #pragma unroll
  for (int q=0;q<4;q++){ av[q] = arow[lane+64*q]; bv[q] = brow[lane+64*q]; }
  for (int l=0;l<10;l++){
    const float* wrow = wp + l*256;
    float s1=0.f, s2=0.f, s3=0.f;
    #pragma unroll
    for (int q=0;q<4;q++){
      float w = wrow[lane+64*q]; float w2v = w*w;
      s1 += w2v*av[q]*bv[q]; s2 += w2v*av[q]*av[q]; s3 += w2v*bv[q]*bv[q];
    }
    for (int off=32; off; off>>=1){
      s1 += __shfl_xor(s1,off,64); s2 += __shfl_xor(s2,off,64); s3 += __shfl_xor(s3,off,64);
    }
    if (lane == 0) mvrow[22 + wv*10 + l] = s1 / fmaxf(sqrtf(s2)*sqrtf(s3), EPSV);
  }
}

// ---------------------------------------------------------------------------
// Mean over time of left/right: XM[b][side*300+d]
// ---------------------------------------------------------------------------
__global__ void k_means(const float* __restrict__ L, const float* __restrict__ R,
                        float* __restrict__ XM){
  int b = blockIdx.x & 3, sideR = blockIdx.x >> 2;
  const float* src = sideR ? R : L;
  int dch = threadIdx.x;
  if (dch >= 300) return;
  float s = 0.f;
  for (int t=0;t<256;t++) s += src[((size_t)(b*256 + t))*300 + dch];
  XM[b*600 + sideR*300 + dch] = s*(1.f/256.f);
}

// ---------------------------------------------------------------------------
// Head: fc1 (tanh), fc2
// ---------------------------------------------------------------------------
__global__ __launch_bounds__(512) void k_fc1(const float* __restrict__ HT_,
                                             const float* __restrict__ XM,
                                             const float* __restrict__ W1T,
                                             const float* __restrict__ b1,
                                             float* __restrict__ X2){
  __shared__ float x[1626];
  int b = blockIdx.x, t = threadIdx.x;
  if (t < 256){
    x[t]       = HT_[(b*2+0)*256 + t];
    x[256+t]   = HT_[(b*2+1)*256 + t];
    x[512+t]   = HT_[((4+b)*2+0)*256 + t];
    x[768+t]   = HT_[((4+b)*2+1)*256 + t];
  }
  if (t == 0){ x[1024] = 0.5f; x[1025] = 0.5f; }
  if (t < 300){ x[1026+t] = XM[b*600 + t]; x[1326+t] = XM[b*600 + 300 + t]; }
  __syncthreads();
  float acc = b1[t];
  for (int k=0;k<1626;k++) acc += x[k]*W1T[(size_t)k*512 + t];
  X2[b*512 + t] = tanhf(acc);
}

__global__ void k_fc2(const float* __restrict__ X2, const float* __restrict__ W2,
                      const float* __restrict__ b2, float* __restrict__ out){
  int b = blockIdx.x, o = threadIdx.x;
  if (o >= 22) return;
  float acc = b2[o];
  const float* xr = X2 + b*512;
  const float* wr = W2 + (size_t)o*512;
  for (int k=0;k<512;k++) acc += xr[k]*wr[k];
  out[b*22 + o] = acc;
}

// ---------------------------------------------------------------------------
extern "C" void kernel_launch(void* const* d_in, const int* in_sizes, int n_in,
                              void* d_out, int out_size, void* d_ws, size_t ws_size,
                              hipStream_t stream) {
  const float* left  = (const float*)d_in[0];
  const float* right = (const float*)d_in[1];
  const float* cWihF = (const float*)d_in[2];
  const float* cWhhF = (const float*)d_in[3];
  const float* cbF   = (const float*)d_in[4];
  const float* cWihB = (const float*)d_in[5];
  const float* cWhhB = (const float*)d_in[6];
  const float* cbB   = (const float*)d_in[7];
  const float* aWihF = (const float*)d_in[8];
  const float* aWhhF = (const float*)d_in[9];
  const float* abF   = (const float*)d_in[10];
  const float* aWihB = (const float*)d_in[11];
  const float* aWhhB = (const float*)d_in[12];
  const float* abB   = (const float*)d_in[13];
  const float* w3 = (const float*)d_in[14];
  const float* w4 = (const float*)d_in[15];
  const float* w5 = (const float*)d_in[16];
  const float* w6 = (const float*)d_in[17];
  const float* w7 = (const float*)d_in[18];
  const float* w8 = (const float*)d_in[19];
  const float* fc1W = (const float*)d_in[20];
  const float* fc1b = (const float*)d_in[21];
  const float* fc2W = (const float*)d_in[22];
  const float* fc2b = (const float*)d_in[23];
  float* out = (float*)d_out;
  float* ws = (float*)d_ws;

  // workspace layout (floats)
  float* WT    = ws;                 // 4 * 262144  (ctx_f, ctx_b, agg_f, agg_b)
  float* PREf  = ws + 1048576;       // 2097152
  float* PREb  = ws + 3145728;       // 2097152
  float* HS    = ws + 5242880;       // 1048576  (8,256,512)
  float* NORM  = ws + 6291456;       // 4096     [(seq*2+d)*256+i]
  float* ATT   = ws + 6295552;       // 524288   [d][b][i][j]
  float* RS    = ws + 6819840;       // 2048     [(d*4+b)*256+i]
  float* RMAX  = ws + 6821888;       // 2048
  float* CS    = ws + 6823936;       // 2048
  float* CMAX  = ws + 6825984;       // 2048
  float* MEANH = ws + 6828032;       // 524288   [d][b][i][h]
  float* MEANP = ws + 7352320;       // 524288   [d][b][j][h]
  float* XH    = ws + 7876608;       // 524288
  float* XP    = ws + 8400896;       // 524288
  float* WN1   = ws + 8925184;       // 20480    [d][b][l][i]
  float* WN2   = ws + 8945664;       // 20480
  float* MM    = ws + 8966144;       // 2621440  [b][l][i][j] (per dir, reused)
  float* MMR   = ws + 11587584;      // 20480    [d][b][l][i]
  float* MMC   = ws + 11608064;      // 20480
  float* MV    = ws + 11628544;      // 126976   (2048,62)
  float* HT    = ws + 11755520;      // 4096     [(seq*2+d)*256+j]
  float* XM    = ws + 11759616;      // 2400
  float* X2    = ws + 11762016;      // 2048
  float* W1T   = ws + 11764064;      // 832512

  // scan exchange buffers live in the (idle-during-scans) MM region
  float* HXB = MM;                   // 8192 floats: [dir][parity][256][8]
  int*   CNT = (int*)(MM + 8192);    // 512 ints:   [dir][256]

  // 1. transposes
  k_transpose<<<dim3(8,32),  dim3(32,32), 0, stream>>>(cWhhF, WT + 0,      1024, 256);
  k_transpose<<<dim3(8,32),  dim3(32,32), 0, stream>>>(cWhhB, WT + 262144, 1024, 256);
  k_transpose<<<dim3(8,32),  dim3(32,32), 0, stream>>>(aWhhF, WT + 524288, 1024, 256);
  k_transpose<<<dim3(8,32),  dim3(32,32), 0, stream>>>(aWhhB, WT + 786432, 1024, 256);
  k_transpose<<<dim3(51,16), dim3(32,32), 0, stream>>>(fc1W, W1T, 512, 1626);

  // 2. ctx input projections (x @ Wih^T + b)
  k_gemm<0><<<dim3(16,16,1),256,0,stream>>>(left, 300,0,0,  cWihF,300,0,0,  PREf,           1024,0,0,
      nullptr,0,0, nullptr,0,0, nullptr,0,0, cbF, 1024,1024,300, 1);
  k_gemm<0><<<dim3(16,16,1),256,0,stream>>>(right,300,0,0,  cWihF,300,0,0,  PREf+1048576,   1024,0,0,
      nullptr,0,0, nullptr,0,0, nullptr,0,0, cbF, 1024,1024,300, 1);
  k_gemm<0><<<dim3(16,16,1),256,0,stream>>>(left, 300,0,0,  cWihB,300,0,0,  PREb,           1024,0,0,
      nullptr,0,0, nullptr,0,0, nullptr,0,0, cbB, 1024,1024,300, 1);
  k_gemm<0><<<dim3(16,16,1),256,0,stream>>>(right,300,0,0,  cWihB,300,0,0,  PREb+1048576,   1024,0,0,
      nullptr,0,0, nullptr,0,0, nullptr,0,0, cbB, 1024,1024,300, 1);

  // 3. ctx scan (8 WGs/dir, LDS-resident weights)
  hipMemsetAsync(CNT, 0, 512*sizeof(int), stream);
  k_scan2<<<16,512,0,stream>>>(PREf, PREb, WT, WT+262144, HXB, CNT, HS, nullptr);

  // 4. row norms
  k_rownorm<<<1024,256,0,stream>>>(HS, NORM);

  // 5. att (cosine matrix), z = d*4+b
  k_gemm<1><<<dim3(4,4,8),256,0,stream>>>(HS,512,256,131072,  HS+524288,512,256,131072,
      ATT,256,262144,65536,  nullptr,0,0,  NORM,256,512,  NORM+2048,256,512,
      nullptr, 256,256,256, 4);

  // 6-7. att reductions
  k_rowred<<<512,256,0,stream>>>(ATT, RS, RMAX, 256);
  k_colred<<<dim3(1,1,8),256,0,stream>>>(ATT, 65536, 256, 256, CS, CMAX);

  // 8. attentive means and maxes
  k_gemm<2><<<dim3(4,4,8),256,0,stream>>>(ATT,256,262144,65536,  HS+524288,512,256,131072,
      MEANH,256,262144,65536,  nullptr,0,0,  RS,1024,256,  nullptr,0,0, nullptr, 256,256,256, 4);
  k_gemm<4><<<dim3(4,4,8),256,0,stream>>>(ATT,256,262144,65536,  HS,512,256,131072,
      MEANP,256,262144,65536,  nullptr,0,0,  CS,1024,256,  nullptr,0,0, nullptr, 256,256,256, 4);
  k_gemm<3><<<dim3(4,4,8),256,0,stream>>>(ATT,256,262144,65536,  HS+524288,512,256,131072,
      XH,256,262144,65536,  nullptr,0,0,  nullptr,0,0,  nullptr,0,0, nullptr, 256,256,256, 4);
  k_gemm<5><<<dim3(4,4,8),256,0,stream>>>(ATT,256,262144,65536,  HS,512,256,131072,
      XP,256,262144,65536,  nullptr,0,0,  nullptr,0,0,  nullptr,0,0, nullptr, 256,256,256, 4);

  // 9. weighted norms
  k_wnorm<<<10240,256,0,stream>>>(HS, w3, w4, WN1, WN2);

  // 10-13. pairwise mm (fw then bw, buffer reused), z = b*10+l
  k_gemm<1><<<dim3(4,4,40),256,0,stream>>>(HS,512,131072,0,  HS+524288,512,131072,0,
      MM,256,655360,65536,  w3,0,256,  WN1,2560,256,  WN2,2560,256,
      nullptr, 256,256,256, 10);
  k_rowred<<<2560,256,0,stream>>>(MM, nullptr, MMR, 256);
  k_colred<<<dim3(1,1,40),256,0,stream>>>(MM, 65536, 256, 256, nullptr, MMC);
  k_gemm<1><<<dim3(4,4,40),256,0,stream>>>(HS+256,512,131072,0,  HS+524288+256,512,131072,0,
      MM,256,655360,65536,  w4,0,256,  WN1+10240,2560,256,  WN2+10240,2560,256,
      nullptr, 256,256,256, 10);
  k_rowred<<<2560,256,0,stream>>>(MM, nullptr, MMR+10240, 256);
  k_colred<<<dim3(1,1,40),256,0,stream>>>(MM, 65536, 256, 256, nullptr, MMC+10240);

  // 14. assemble mv (2048 rows x 62)
  k_mv<<<2048,256,0,stream>>>(HS, MEANH, MEANP, XH, XP, RS, RMAX, CS, CMAX,
                              MMR, MMC, w5, w6, w7, w8, MV);

  // 15. agg projections
  k_gemm<0><<<dim3(16,32,1),256,0,stream>>>(MV,62,0,0,  aWihF,62,0,0,  PREf,1024,0,0,
      nullptr,0,0, nullptr,0,0, nullptr,0,0, abF, 2048,1024,62, 1);
  k_gemm<0><<<dim3(16,32,1),256,0,stream>>>(MV,62,0,0,  aWihB,62,0,0,  PREb,1024,0,0,
      nullptr,0,0, nullptr,0,0, nullptr,0,0, abB, 2048,1024,62, 1);

  // 16. agg scan (keep only final h)
  hipMemsetAsync(CNT, 0, 512*sizeof(int), stream);
  k_scan2<<<16,512,0,stream>>>(PREf, PREb, WT+524288, WT+786432, HXB, CNT, nullptr, HT);

  // 17-19. head
  k_means<<<8,320,0,stream>>>(left, right, XM);
  k_fc1<<<4,512,0,stream>>>(HT, XM, W1T, fc1b, X2);
  k_fc2<<<4,64,0,stream>>>(X2, fc2W, fc2b, out);
}